// Round 8
// baseline (198.169 us; speedup 1.0000x reference)
//
#include <hip/hip_runtime.h>
#include <stdint.h>
#include <stddef.h>

typedef short bfrag __attribute__((ext_vector_type(8)));
typedef float f32x4 __attribute__((ext_vector_type(4)));

#define NSEQ 7
// feats packed in MFMA A-fragment order: [btile(1024)][step(18)][lane(64)][j(8)] bf16
// value = feat[btile*16 + (lane&15)][k], k = step*32 + (lane>>4)*8 + j

__constant__ int c_ks[5] = {1, 3, 5, 7, 9};

// per-ksize active MFMA K-steps (B is exactly zero outside): s in [lo, lo+n)
#define SLO0 3
#define SLO1 2
#define SLO2 1
#define SLO3 0
#define SLO4 0
#define SN0 1
#define SN1 3
#define SN2 5
#define SN3 6
#define SN4 7

static __device__ __forceinline__ unsigned short f2bf(float f) {
  unsigned int u = __float_as_uint(f);
  u += 0x7FFFu + ((u >> 16) & 1u);   // RNE
  return (unsigned short)(u >> 16);
}

// ---------------- prep: pack conv weights + lin1 into B-fragment layout ----------
struct PrepArgs {
  const float* Wk[5];
  const float* lin1_w;
  bfrag* Wpack;
  bfrag* lin1pack;
};

__global__ __launch_bounds__(256) void prep_kernel(PrepArgs a) {
  int tid = blockIdx.x * 256 + threadIdx.x;
  const int NW = NSEQ * 5 * 7 * 64;
  if (tid < NW) {
    int lane = tid & 63, rest = tid >> 6;
    int step = rest % 7, nt = (rest / 7) % 5, seq = rest / 35;
    int quad = lane >> 4, f = lane & 15;
    int ks = c_ks[nt], off = (9 - ks) >> 1;
    const float* W = a.Wk[nt];
    bfrag s;
#pragma unroll
    for (int j = 0; j < 8; ++j) {
      int k = step * 32 + quad * 8 + j;
      int t = k / 24, c = k % 24;
      int tap = t - off;
      float val = 0.f;
      if (c < 20 && tap >= 0 && tap < ks)
        val = W[((seq * 16 + f) * 20 + c) * ks + tap] * 0.2f;  // fold /5
      s[j] = (short)f2bf(val);
    }
    a.Wpack[tid] = s;
  } else if (tid < NW + 4 * 18 * 64) {
    int t2 = tid - NW;
    int lane = t2 & 63, rest = t2 >> 6;
    int step = rest % 18, nt = rest / 18;
    int quad = lane >> 4, col = lane & 15;
    int n = nt * 16 + col;
    bfrag s;
#pragma unroll
    for (int j = 0; j < 8; ++j) {
      int k = step * 32 + quad * 8 + j;
      float val = (k < 560) ? a.lin1_w[n * 560 + k] : 0.f;  // zero rows k>=560 make feats pad inert
      s[j] = (short)f2bf(val);
    }
    a.lin1pack[t2] = s;
  }
}

// ---------------- conv+relu+gmax: im2col MFMA, one dispatch, per-seq constexpr ----------
struct ConvArgs {
  const float* x[NSEQ];
  const bfrag* Wpack;
  unsigned short* feats;   // packed A-frag layout, see top
};

static __device__ __forceinline__ void store_feat(unsigned short* feats, int b, int k, float v) {
  int step = k >> 5, q = (k >> 3) & 3, j = k & 7;
  feats[((size_t)(b >> 4) * 18 + step) * 512 + (q * 16 + (b & 15)) * 8 + j] = f2bf(v);
}

// MTc==1: Lp = 1<<SHIFTc <= 16. MTc==2: seq6 (L=18), two OVERLAPPING dense 16-row
// tiles per sample (rows 0-15 and 2-17; overlap idempotent under max).
template <int Lc, int SHIFTc, int MTc, int TBBv, int Pv>
__device__ __forceinline__ void conv_body(unsigned short* xl, const ConvArgs& a,
                                          const int seq, const int b0) {
  const int tid = threadIdx.x;
  const float* xg = a.x[seq];

  // Phase A (disjoint writes, single barrier after):
  // 1) zero ONLY halo/pad rows per sample: rows [0,4) and [4+Lc, Pv), full 24-width.
  //    One 24-halfword row = 48 B = 3 uint4 (16B-aligned since 48 | row pitch).
  {
    constexpr int H1 = 4 * 3;                  // leading-halo uint4s
    constexpr int H2 = (Pv - 4 - Lc) * 3;      // trailing-halo uint4s
    uint4* xw = (uint4*)xl;
    for (int i = tid; i < TBBv * (H1 + H2); i += 256) {
      int b = i / (H1 + H2), w = i % (H1 + H2);
      int off = b * Pv * 3 + ((w < H1) ? w : (4 + Lc) * 3 + (w - H1));
      xw[off] = uint4{0, 0, 0, 0};
    }
  }
  // 2) stage x -> bf16 [b][pos=xi+4][c] for data rows; c in [20,24) zeroed here too.
  for (int r = tid; r < TBBv * 24; r += 256) {
    int b = r / 24, c = r % 24;
    unsigned short* dst = xl + (b * Pv + 4) * 24 + c;
    if (c < 20) {
      const float* src = xg + ((size_t)(b0 + b) * 20 + c) * Lc;
#pragma unroll
      for (int xi = 0; xi < Lc; ++xi) dst[xi * 24] = f2bf(src[xi]);
    } else {
#pragma unroll
      for (int xi = 0; xi < Lc; ++xi) dst[xi * 24] = 0;
    }
  }
  __syncthreads();

  const int wave = tid >> 6, lane = tid & 63, quad = lane >> 4, m = lane & 15;

  // preload the 22 non-zero B fragments for this seq
  const bfrag* wp = a.Wpack + (size_t)(seq * 5 * 7) * 64 + lane;
  bfrag Bf[22];
  {
    int bi = 0;
#pragma unroll
    for (int i = 0; i < SN0; ++i) Bf[bi++] = wp[(0 * 7 + SLO0 + i) * 64];
#pragma unroll
    for (int i = 0; i < SN1; ++i) Bf[bi++] = wp[(1 * 7 + SLO1 + i) * 64];
#pragma unroll
    for (int i = 0; i < SN2; ++i) Bf[bi++] = wp[(2 * 7 + SLO2 + i) * 64];
#pragma unroll
    for (int i = 0; i < SN3; ++i) Bf[bi++] = wp[(3 * 7 + SLO3 + i) * 64];
#pragma unroll
    for (int i = 0; i < SN4; ++i) Bf[bi++] = wp[(4 * 7 + SLO4 + i) * 64];
  }
  // Bf base offsets per nt: {0, 1, 4, 9, 15}

  constexpr int njobs = (MTc == 2) ? TBBv : ((TBBv << SHIFTc) >> 4);  // multiple of 8
  constexpr int bpt = (MTc == 1 && SHIFTc == 3) ? 2 : 1;
  constexpr int lmask = (1 << SHIFTc) - 1;

  // JB=2: two M-tiles per iteration share B and interleave -> 2x ILP window
  for (int jj = wave * 2; jj < njobs; jj += 8) {
    float va[2][5] = {{0.f, 0.f, 0.f, 0.f, 0.f}, {0.f, 0.f, 0.f, 0.f, 0.f}};
#pragma unroll
    for (int sub = 0; sub < MTc; ++sub) {
      const unsigned short* arow[2];
#pragma unroll
      for (int jd = 0; jd < 2; ++jd) {
        int job = jj + jd, bl, l;
        if (MTc == 2) { bl = job; l = sub * 2 + m; }
        else { int rr = job * 16 + m; bl = rr >> SHIFTc; l = rr & lmask; }
        arow[jd] = &xl[(bl * Pv + l) * 24 + quad * 8];
      }
      f32x4 acc[2][5];
#pragma unroll
      for (int jd = 0; jd < 2; ++jd)
#pragma unroll
        for (int g = 0; g < 5; ++g) acc[jd][g] = f32x4{0.f, 0.f, 0.f, 0.f};
#pragma unroll
      for (int s = 0; s < 7; ++s) {
#pragma unroll
        for (int jd = 0; jd < 2; ++jd) {
          bfrag Af = *(const bfrag*)(arow[jd] + s * 32);
          if (s >= SLO0 && s < SLO0 + SN0)
            acc[jd][0] = __builtin_amdgcn_mfma_f32_16x16x32_bf16(Af, Bf[0 + s - SLO0], acc[jd][0], 0, 0, 0);
          if (s >= SLO1 && s < SLO1 + SN1)
            acc[jd][1] = __builtin_amdgcn_mfma_f32_16x16x32_bf16(Af, Bf[1 + s - SLO1], acc[jd][1], 0, 0, 0);
          if (s >= SLO2 && s < SLO2 + SN2)
            acc[jd][2] = __builtin_amdgcn_mfma_f32_16x16x32_bf16(Af, Bf[4 + s - SLO2], acc[jd][2], 0, 0, 0);
          if (s >= SLO3 && s < SLO3 + SN3)
            acc[jd][3] = __builtin_amdgcn_mfma_f32_16x16x32_bf16(Af, Bf[9 + s - SLO3], acc[jd][3], 0, 0, 0);
          acc[jd][4] = __builtin_amdgcn_mfma_f32_16x16x32_bf16(Af, Bf[15 + s], acc[jd][4], 0, 0, 0);
        }
      }
      // relu+max fold; mask output rows l >= Lc (job-invariant, constant-folds when dense)
#pragma unroll
      for (int jd = 0; jd < 2; ++jd)
#pragma unroll
        for (int g = 0; g < 5; ++g)
#pragma unroll
          for (int r4 = 0; r4 < 4; ++r4) {
            bool ok = (MTc == 2) ? true : (((quad * 4 + r4) & lmask) < Lc);
            va[jd][g] = fmaxf(va[jd][g], ok ? acc[jd][g][r4] : 0.f);
          }
    }
    // cross-lane reductions + stores (two independent chains overlap)
#pragma unroll
    for (int jd = 0; jd < 2; ++jd) {
      int job = jj + jd;
      float v0 = va[jd][0], v1 = va[jd][1], v2 = va[jd][2], v3 = va[jd][3], v4 = va[jd][4];
      v0 = fmaxf(v0, __shfl_xor(v0, 16));
      v1 = fmaxf(v1, __shfl_xor(v1, 16));
      v2 = fmaxf(v2, __shfl_xor(v2, 16));
      v3 = fmaxf(v3, __shfl_xor(v3, 16));
      v4 = fmaxf(v4, __shfl_xor(v4, 16));
      if (bpt == 1) {
        v0 = fmaxf(v0, __shfl_xor(v0, 32));
        v1 = fmaxf(v1, __shfl_xor(v1, 32));
        v2 = fmaxf(v2, __shfl_xor(v2, 32));
        v3 = fmaxf(v3, __shfl_xor(v3, 32));
        v4 = fmaxf(v4, __shfl_xor(v4, 32));
        if (lane < 16) {
          int b = b0 + job, kb = seq * 80 + lane;
          store_feat(a.feats, b, kb, v0);      store_feat(a.feats, b, kb + 16, v1);
          store_feat(a.feats, b, kb + 32, v2); store_feat(a.feats, b, kb + 48, v3);
          store_feat(a.feats, b, kb + 64, v4);
        }
      } else {
        // out rows 0-7 (quads 0,1) -> even sample ; rows 8-15 (quads 2,3) -> odd
        if ((lane & 16) == 0) {
          int b = b0 + job * 2 + (lane >> 5), kb = seq * 80 + (lane & 15);
          store_feat(a.feats, b, kb, v0);      store_feat(a.feats, b, kb + 16, v1);
          store_feat(a.feats, b, kb + 32, v2); store_feat(a.feats, b, kb + 48, v3);
          store_feat(a.feats, b, kb + 64, v4);
        }
      }
    }
  }
}

__global__ __launch_bounds__(256, 3) void conv_kernel(ConvArgs a) {
  __shared__ __align__(16) unsigned short xl[32 * 25 * 24];   // 38.4 KB (seq6 uses 31.5 KB)
  const int bid = blockIdx.x;
  if (bid < 3072) {
    const int seq = bid >> 9, b0 = (bid & 511) * 32;
    switch (seq) {
      case 0: conv_body<12, 4, 1, 32, 25>(xl, a, 0, b0); break;
      case 1: conv_body< 7, 3, 1, 32, 25>(xl, a, 1, b0); break;
      case 2: conv_body< 8, 3, 1, 32, 25>(xl, a, 2, b0); break;
      case 3: conv_body<16, 4, 1, 32, 25>(xl, a, 3, b0); break;
      case 4: conv_body< 6, 3, 1, 32, 25>(xl, a, 4, b0); break;
      default: conv_body< 7, 3, 1, 32, 25>(xl, a, 5, b0); break;
    }
  } else {
    conv_body<18, 5, 2, 16, 41>(xl, a, 6, (bid - 3072) * 16);
  }
}

// ---------------- MLP: feats(packed) -> sigmoid(@lin1^T+b1) -> @lin2^T+b2 ----------------
struct MlpArgs {
  const bfrag* feats;      // packed A-frag layout
  const bfrag* lin1pack;
  const float* lin1_b;
  const float* lin2_w;
  const float* lin2_b;
  float* out;
};

__global__ __launch_bounds__(256, 4) void mlp_kernel(MlpArgs a) {
  __shared__ float h[16 * 68];
  __shared__ float w2[64];
  const int tid = threadIdx.x;
  const int b0 = blockIdx.x * 16;
  if (tid < 64) w2[tid] = a.lin2_w[tid];
  const int wave = tid >> 6, lane = tid & 63, quad = lane >> 4, m = lane & 15;
  const int nt = wave;                     // one n-tile per wave
  // B fragments register-resident (18 x 4 VGPR = 72)
  bfrag Bf[18];
#pragma unroll
  for (int s = 0; s < 18; ++s) Bf[s] = a.lin1pack[(nt * 18 + s) * 64 + lane];
  const bfrag* ap = a.feats + (size_t)blockIdx.x * 18 * 64 + lane;  // coalesced 16B/lane
  f32x4 acc = {0.f, 0.f, 0.f, 0.f};
#pragma unroll
  for (int s = 0; s < 18; ++s)
    acc = __builtin_amdgcn_mfma_f32_16x16x32_bf16(ap[s * 64], Bf[s], acc, 0, 0, 0);
  int n = nt * 16 + m;
  float bias = a.lin1_b[n];
#pragma unroll
  for (int r = 0; r < 4; ++r) {
    float pre = acc[r] + bias;
    h[(quad * 4 + r) * 68 + n] = 1.f / (1.f + __expf(-pre));
  }
  __syncthreads();
  int bl = tid >> 4, q = tid & 15;         // 16 threads per sample, 4 h each
  const float* hr = &h[bl * 68 + q * 4];
  float s = hr[0] * w2[q * 4] + hr[1] * w2[q * 4 + 1] + hr[2] * w2[q * 4 + 2] + hr[3] * w2[q * 4 + 3];
  s += __shfl_xor(s, 1);
  s += __shfl_xor(s, 2);
  s += __shfl_xor(s, 4);
  s += __shfl_xor(s, 8);
  if (q == 0) a.out[b0 + bl] = s + a.lin2_b[0];
}

// ---------------- launch ----------------
extern "C" void kernel_launch(void* const* d_in, const int* in_sizes, int n_in,
                              void* d_out, int out_size, void* d_ws, size_t ws_size,
                              hipStream_t stream) {
  (void)in_sizes; (void)n_in; (void)out_size; (void)ws_size;
  char* ws = (char*)d_ws;
  bfrag* Wpack = (bfrag*)(ws + 0);                 // 15680*16 = 250,880 B
  bfrag* lin1pack = (bfrag*)(ws + 262144);         // 4608*16  =  73,728 B
  unsigned short* feats = (unsigned short*)(ws + 393216);  // 1024*18*64*16 = 18.87 MB

  PrepArgs pa;
  for (int j = 0; j < 5; ++j) pa.Wk[j] = (const float*)d_in[7 + j];
  pa.lin1_w = (const float*)d_in[12];
  pa.Wpack = Wpack;
  pa.lin1pack = lin1pack;
  prep_kernel<<<80, 256, 0, stream>>>(pa);

  ConvArgs ca;
  for (int i = 0; i < NSEQ; ++i) ca.x[i] = (const float*)d_in[i];
  ca.Wpack = Wpack;
  ca.feats = feats;
  // 3072 blocks: seqs 0-5 (TBB=32) ; 1024 blocks: seq 6 (TBB=16)
  conv_kernel<<<4096, 256, 0, stream>>>(ca);

  MlpArgs ma;
  ma.feats = (const bfrag*)feats;
  ma.lin1pack = lin1pack;
  ma.lin1_b = (const float*)d_in[13];
  ma.lin2_w = (const float*)d_in[14];
  ma.lin2_b = (const float*)d_in[15];
  ma.out = (float*)d_out;
  mlp_kernel<<<1024, 256, 0, stream>>>(ma);
}

// Round 9
// 186.902 us; speedup vs baseline: 1.0603x; 1.0603x over previous
//
#include <hip/hip_runtime.h>
#include <stdint.h>
#include <stddef.h>

typedef short bfrag __attribute__((ext_vector_type(8)));
typedef float f32x4 __attribute__((ext_vector_type(4)));

#define NSEQ 7
// feats packed in MFMA A-fragment order: [btile(1024)][step(18)][lane(64)][j(8)] bf16
// value = feat[btile*16 + (lane&15)][k], k = step*32 + (lane>>4)*8 + j

__constant__ int c_ks[5] = {1, 3, 5, 7, 9};

// per-ksize active MFMA K-steps (B is exactly zero outside): s in [lo, lo+n)
#define SLO0 3
#define SLO1 2
#define SLO2 1
#define SLO3 0
#define SLO4 0
#define SN0 1
#define SN1 3
#define SN2 5
#define SN3 6
#define SN4 7

static __device__ __forceinline__ unsigned short f2bf(float f) {
  unsigned int u = __float_as_uint(f);
  u += 0x7FFFu + ((u >> 16) & 1u);   // RNE
  return (unsigned short)(u >> 16);
}

// ---------------- prep: pack conv weights + lin1 into B-fragment layout ----------
struct PrepArgs {
  const float* Wk[5];
  const float* lin1_w;
  bfrag* Wpack;
  bfrag* lin1pack;
};

__global__ __launch_bounds__(256) void prep_kernel(PrepArgs a) {
  int tid = blockIdx.x * 256 + threadIdx.x;
  const int NW = NSEQ * 5 * 7 * 64;
  if (tid < NW) {
    int lane = tid & 63, rest = tid >> 6;
    int step = rest % 7, nt = (rest / 7) % 5, seq = rest / 35;
    int quad = lane >> 4, f = lane & 15;
    int ks = c_ks[nt], off = (9 - ks) >> 1;
    const float* W = a.Wk[nt];
    bfrag s;
#pragma unroll
    for (int j = 0; j < 8; ++j) {
      int k = step * 32 + quad * 8 + j;
      int t = k / 24, c = k % 24;
      int tap = t - off;
      float val = 0.f;
      if (c < 20 && tap >= 0 && tap < ks)
        val = W[((seq * 16 + f) * 20 + c) * ks + tap] * 0.2f;  // fold /5
      s[j] = (short)f2bf(val);
    }
    a.Wpack[tid] = s;
  } else if (tid < NW + 4 * 18 * 64) {
    int t2 = tid - NW;
    int lane = t2 & 63, rest = t2 >> 6;
    int step = rest % 18, nt = rest / 18;
    int quad = lane >> 4, col = lane & 15;
    int n = nt * 16 + col;
    bfrag s;
#pragma unroll
    for (int j = 0; j < 8; ++j) {
      int k = step * 32 + quad * 8 + j;
      float val = (k < 560) ? a.lin1_w[n * 560 + k] : 0.f;  // zero rows k>=560 make feats pad inert
      s[j] = (short)f2bf(val);
    }
    a.lin1pack[t2] = s;
  }
}

// ---------------- conv+relu+gmax: im2col MFMA, one dispatch, per-seq constexpr ----------
struct ConvArgs {
  const float* x[NSEQ];
  const bfrag* Wpack;
  unsigned short* feats;   // packed A-frag layout, see top
};

static __device__ __forceinline__ void store_feat(unsigned short* feats, int b, int k, float v) {
  int step = k >> 5, q = (k >> 3) & 3, j = k & 7;
  feats[((size_t)(b >> 4) * 18 + step) * 512 + (q * 16 + (b & 15)) * 8 + j] = f2bf(v);
}

// MTc==1: Lp = 1<<SHIFTc <= 16. MTc==2: seq6 (L=18), two OVERLAPPING dense 16-row
// tiles per sample (rows 0-15 and 2-17; overlap idempotent under max).
template <int Lc, int SHIFTc, int MTc, int TBBv, int Pv>
__device__ __forceinline__ void conv_body(unsigned short* xl, const ConvArgs& a,
                                          const int seq, const int b0) {
  const int tid = threadIdx.x;
  const float* xg = a.x[seq];

  // zero staging region (covers c-pad, l-pad, halo) — vectorized
  for (int i = tid; i < TBBv * Pv * 24 / 8; i += 256) ((uint4*)xl)[i] = uint4{0, 0, 0, 0};
  __syncthreads();
  // stage x -> bf16 [b][pos=xi+4][c]
  for (int r = tid; r < TBBv * 20; r += 256) {
    int b = r / 20, c = r % 20;
    const float* src = xg + ((size_t)(b0 + b) * 20 + c) * Lc;
    unsigned short* dst = xl + (b * Pv + 4) * 24 + c;
#pragma unroll
    for (int xi = 0; xi < Lc; ++xi) dst[xi * 24] = f2bf(src[xi]);
  }
  __syncthreads();

  const int wave = tid >> 6, lane = tid & 63, quad = lane >> 4, m = lane & 15;

  // preload the 22 non-zero B fragments for this seq and PIN them in VGPRs:
  // without the pin the allocator sinks these loads into the job loop
  // (observed VGPR_Count 64-84 < the 88 needed), re-issuing 22 VMEM loads
  // per tile — the latency that capped MfmaUtil at ~21%.
  const bfrag* wp = a.Wpack + (size_t)(seq * 5 * 7) * 64 + lane;
  bfrag Bf[22];
  {
    int bi = 0;
#pragma unroll
    for (int i = 0; i < SN0; ++i) Bf[bi++] = wp[(0 * 7 + SLO0 + i) * 64];
#pragma unroll
    for (int i = 0; i < SN1; ++i) Bf[bi++] = wp[(1 * 7 + SLO1 + i) * 64];
#pragma unroll
    for (int i = 0; i < SN2; ++i) Bf[bi++] = wp[(2 * 7 + SLO2 + i) * 64];
#pragma unroll
    for (int i = 0; i < SN3; ++i) Bf[bi++] = wp[(3 * 7 + SLO3 + i) * 64];
#pragma unroll
    for (int i = 0; i < SN4; ++i) Bf[bi++] = wp[(4 * 7 + SLO4 + i) * 64];
  }
#pragma unroll
  for (int i = 0; i < 22; ++i) __asm__ volatile("" : "+v"(Bf[i]));
  // Bf base offsets per nt: {0, 1, 4, 9, 15}

  constexpr int njobs = (MTc == 2) ? TBBv : ((TBBv << SHIFTc) >> 4);
  constexpr int bpt = (MTc == 1 && SHIFTc == 3) ? 2 : 1;
  constexpr int lmask = (1 << SHIFTc) - 1;

  for (int job = wave; job < njobs; job += 4) {
    float v0 = 0.f, v1 = 0.f, v2 = 0.f, v3 = 0.f, v4 = 0.f;
#pragma unroll
    for (int sub = 0; sub < MTc; ++sub) {
      int bl, l;
      if (MTc == 2) { bl = job; l = sub * 2 + m; }          // dense overlapping tiles
      else { int r = job * 16 + m; bl = r >> SHIFTc; l = r & lmask; }
      const unsigned short* arow = &xl[(bl * Pv + l) * 24 + quad * 8];
      f32x4 acc0 = {0.f, 0.f, 0.f, 0.f}, acc1 = acc0, acc2 = acc0, acc3 = acc0, acc4 = acc0;
#pragma unroll
      for (int s = 0; s < 7; ++s) {
        bfrag Af = *(const bfrag*)(arow + s * 32);
        if (s >= SLO0 && s < SLO0 + SN0)
          acc0 = __builtin_amdgcn_mfma_f32_16x16x32_bf16(Af, Bf[0 + s - SLO0], acc0, 0, 0, 0);
        if (s >= SLO1 && s < SLO1 + SN1)
          acc1 = __builtin_amdgcn_mfma_f32_16x16x32_bf16(Af, Bf[1 + s - SLO1], acc1, 0, 0, 0);
        if (s >= SLO2 && s < SLO2 + SN2)
          acc2 = __builtin_amdgcn_mfma_f32_16x16x32_bf16(Af, Bf[4 + s - SLO2], acc2, 0, 0, 0);
        if (s >= SLO3 && s < SLO3 + SN3)
          acc3 = __builtin_amdgcn_mfma_f32_16x16x32_bf16(Af, Bf[9 + s - SLO3], acc3, 0, 0, 0);
        acc4 = __builtin_amdgcn_mfma_f32_16x16x32_bf16(Af, Bf[15 + s], acc4, 0, 0, 0);
      }
      // relu+max fold; mask output rows l >= Lc (constant-folds where dense)
#pragma unroll
      for (int r4 = 0; r4 < 4; ++r4) {
        bool ok = (MTc == 2) ? true : (((quad * 4 + r4) & lmask) < Lc);
        v0 = fmaxf(v0, ok ? acc0[r4] : 0.f);
        v1 = fmaxf(v1, ok ? acc1[r4] : 0.f);
        v2 = fmaxf(v2, ok ? acc2[r4] : 0.f);
        v3 = fmaxf(v3, ok ? acc3[r4] : 0.f);
        v4 = fmaxf(v4, ok ? acc4[r4] : 0.f);
      }
    }
    v0 = fmaxf(v0, __shfl_xor(v0, 16));
    v1 = fmaxf(v1, __shfl_xor(v1, 16));
    v2 = fmaxf(v2, __shfl_xor(v2, 16));
    v3 = fmaxf(v3, __shfl_xor(v3, 16));
    v4 = fmaxf(v4, __shfl_xor(v4, 16));
    if (bpt == 1) {
      v0 = fmaxf(v0, __shfl_xor(v0, 32));
      v1 = fmaxf(v1, __shfl_xor(v1, 32));
      v2 = fmaxf(v2, __shfl_xor(v2, 32));
      v3 = fmaxf(v3, __shfl_xor(v3, 32));
      v4 = fmaxf(v4, __shfl_xor(v4, 32));
      if (lane < 16) {
        int b = b0 + job, kb = seq * 80 + lane;
        store_feat(a.feats, b, kb, v0);      store_feat(a.feats, b, kb + 16, v1);
        store_feat(a.feats, b, kb + 32, v2); store_feat(a.feats, b, kb + 48, v3);
        store_feat(a.feats, b, kb + 64, v4);
      }
    } else {
      // out rows 0-7 (quads 0,1) -> even sample ; rows 8-15 (quads 2,3) -> odd
      if ((lane & 16) == 0) {
        int b = b0 + job * 2 + (lane >> 5), kb = seq * 80 + (lane & 15);
        store_feat(a.feats, b, kb, v0);      store_feat(a.feats, b, kb + 16, v1);
        store_feat(a.feats, b, kb + 32, v2); store_feat(a.feats, b, kb + 48, v3);
        store_feat(a.feats, b, kb + 64, v4);
      }
    }
  }
}

__global__ __launch_bounds__(256, 3) void conv_kernel(ConvArgs a) {
  __shared__ __align__(16) unsigned short xl[32 * 25 * 24];   // 38.4 KB (seq6 uses 31.5 KB)
  const int bid = blockIdx.x;
  if (bid < 3072) {
    const int seq = bid >> 9, b0 = (bid & 511) * 32;
    switch (seq) {
      case 0: conv_body<12, 4, 1, 32, 25>(xl, a, 0, b0); break;
      case 1: conv_body< 7, 3, 1, 32, 25>(xl, a, 1, b0); break;
      case 2: conv_body< 8, 3, 1, 32, 25>(xl, a, 2, b0); break;
      case 3: conv_body<16, 4, 1, 32, 25>(xl, a, 3, b0); break;
      case 4: conv_body< 6, 3, 1, 32, 25>(xl, a, 4, b0); break;
      default: conv_body< 7, 3, 1, 32, 25>(xl, a, 5, b0); break;
    }
  } else {
    conv_body<18, 5, 2, 16, 41>(xl, a, 6, (bid - 3072) * 16);
  }
}

// ---------------- MLP: feats(packed) -> sigmoid(@lin1^T+b1) -> @lin2^T+b2 ----------------
struct MlpArgs {
  const bfrag* feats;      // packed A-frag layout
  const bfrag* lin1pack;
  const float* lin1_b;
  const float* lin2_w;
  const float* lin2_b;
  float* out;
};

__global__ __launch_bounds__(256, 4) void mlp_kernel(MlpArgs a) {
  __shared__ float h[16 * 68];
  __shared__ float w2[64];
  const int tid = threadIdx.x;
  const int b0 = blockIdx.x * 16;
  if (tid < 64) w2[tid] = a.lin2_w[tid];
  const int wave = tid >> 6, lane = tid & 63, quad = lane >> 4, m = lane & 15;
  const int nt = wave;                     // one n-tile per wave
  // B fragments register-resident (18 x 4 VGPR = 72), pinned
  bfrag Bf[18];
#pragma unroll
  for (int s = 0; s < 18; ++s) Bf[s] = a.lin1pack[(nt * 18 + s) * 64 + lane];
#pragma unroll
  for (int s = 0; s < 18; ++s) __asm__ volatile("" : "+v"(Bf[s]));
  const bfrag* ap = a.feats + (size_t)blockIdx.x * 18 * 64 + lane;  // coalesced 16B/lane
  f32x4 acc = {0.f, 0.f, 0.f, 0.f};
#pragma unroll
  for (int s = 0; s < 18; ++s)
    acc = __builtin_amdgcn_mfma_f32_16x16x32_bf16(ap[s * 64], Bf[s], acc, 0, 0, 0);
  int n = nt * 16 + m;
  float bias = a.lin1_b[n];
#pragma unroll
  for (int r = 0; r < 4; ++r) {
    float pre = acc[r] + bias;
    h[(quad * 4 + r) * 68 + n] = 1.f / (1.f + __expf(-pre));
  }
  __syncthreads();
  int bl = tid >> 4, q = tid & 15;         // 16 threads per sample, 4 h each
  const float* hr = &h[bl * 68 + q * 4];
  float s = hr[0] * w2[q * 4] + hr[1] * w2[q * 4 + 1] + hr[2] * w2[q * 4 + 2] + hr[3] * w2[q * 4 + 3];
  s += __shfl_xor(s, 1);
  s += __shfl_xor(s, 2);
  s += __shfl_xor(s, 4);
  s += __shfl_xor(s, 8);
  if (q == 0) a.out[b0 + bl] = s + a.lin2_b[0];
}

// ---------------- launch ----------------
extern "C" void kernel_launch(void* const* d_in, const int* in_sizes, int n_in,
                              void* d_out, int out_size, void* d_ws, size_t ws_size,
                              hipStream_t stream) {
  (void)in_sizes; (void)n_in; (void)out_size; (void)ws_size;
  char* ws = (char*)d_ws;
  bfrag* Wpack = (bfrag*)(ws + 0);                 // 15680*16 = 250,880 B
  bfrag* lin1pack = (bfrag*)(ws + 262144);         // 4608*16  =  73,728 B
  unsigned short* feats = (unsigned short*)(ws + 393216);  // 1024*18*64*16 = 18.87 MB

  PrepArgs pa;
  for (int j = 0; j < 5; ++j) pa.Wk[j] = (const float*)d_in[7 + j];
  pa.lin1_w = (const float*)d_in[12];
  pa.Wpack = Wpack;
  pa.lin1pack = lin1pack;
  prep_kernel<<<80, 256, 0, stream>>>(pa);

  ConvArgs ca;
  for (int i = 0; i < NSEQ; ++i) ca.x[i] = (const float*)d_in[i];
  ca.Wpack = Wpack;
  ca.feats = feats;
  // 3072 blocks: seqs 0-5 (TBB=32) ; 1024 blocks: seq 6 (TBB=16)
  conv_kernel<<<4096, 256, 0, stream>>>(ca);

  MlpArgs ma;
  ma.feats = (const bfrag*)feats;
  ma.lin1pack = lin1pack;
  ma.lin1_b = (const float*)d_in[13];
  ma.lin2_w = (const float*)d_in[14];
  ma.lin2_b = (const float*)d_in[15];
  ma.out = (float*)d_out;
  mlp_kernel<<<1024, 256, 0, stream>>>(ma);
}

// Round 10
// 182.140 us; speedup vs baseline: 1.0880x; 1.0261x over previous
//
#include <hip/hip_runtime.h>
#include <stdint.h>
#include <stddef.h>

typedef short bfrag __attribute__((ext_vector_type(8)));
typedef float f32x4 __attribute__((ext_vector_type(4)));

#define NSEQ 7
// feats packed in MFMA A-fragment order: [btile(1024)][step(18)][lane(64)][j(8)] bf16
// value = feat[btile*16 + (lane&15)][k], k = step*32 + (lane>>4)*8 + j

__constant__ int c_ks[5] = {1, 3, 5, 7, 9};

// per-ksize active MFMA K-steps (B is exactly zero outside): s in [lo, lo+n)
#define SLO0 3
#define SLO1 2
#define SLO2 1
#define SLO3 0
#define SLO4 0
#define SN0 1
#define SN1 3
#define SN2 5
#define SN3 6
#define SN4 7

// shared-memory layout (halfwords): xl slab [0, 19200) ; zero scratch [19200, 19456) ;
// seq6 leftover partials (float[16][80]) overlaid at [19456, 22016)
#define XL_HW 22016
#define ZOFF 19200
#define PART_OFF 19456

static __device__ __forceinline__ unsigned short f2bf(float f) {
  unsigned int u = __float_as_uint(f);
  u += 0x7FFFu + ((u >> 16) & 1u);   // RNE
  return (unsigned short)(u >> 16);
}

// ---------------- prep: pack conv weights + lin1 into B-fragment layout ----------
struct PrepArgs {
  const float* Wk[5];
  const float* lin1_w;
  bfrag* Wpack;
  bfrag* lin1pack;
};

__global__ __launch_bounds__(256) void prep_kernel(PrepArgs a) {
  int tid = blockIdx.x * 256 + threadIdx.x;
  const int NW = NSEQ * 5 * 7 * 64;
  if (tid < NW) {
    int lane = tid & 63, rest = tid >> 6;
    int step = rest % 7, nt = (rest / 7) % 5, seq = rest / 35;
    int quad = lane >> 4, f = lane & 15;
    int ks = c_ks[nt], off = (9 - ks) >> 1;
    const float* W = a.Wk[nt];
    bfrag s;
#pragma unroll
    for (int j = 0; j < 8; ++j) {
      int k = step * 32 + quad * 8 + j;
      int t = k / 24, c = k % 24;
      int tap = t - off;
      float val = 0.f;
      if (c < 20 && tap >= 0 && tap < ks)
        val = W[((seq * 16 + f) * 20 + c) * ks + tap] * 0.2f;  // fold /5
      s[j] = (short)f2bf(val);
    }
    a.Wpack[tid] = s;
  } else if (tid < NW + 4 * 18 * 64) {
    int t2 = tid - NW;
    int lane = t2 & 63, rest = t2 >> 6;
    int step = rest % 18, nt = rest / 18;
    int quad = lane >> 4, col = lane & 15;
    int n = nt * 16 + col;
    bfrag s;
#pragma unroll
    for (int j = 0; j < 8; ++j) {
      int k = step * 32 + quad * 8 + j;
      float val = (k < 560) ? a.lin1_w[n * 560 + k] : 0.f;  // zero rows k>=560 make feats pad inert
      s[j] = (short)f2bf(val);
    }
    a.lin1pack[t2] = s;
  }
}

// ---------------- conv+relu+gmax: im2col MFMA, one dispatch, per-seq constexpr ----------
struct ConvArgs {
  const float* x[NSEQ];
  const bfrag* Wpack;
  unsigned short* feats;   // packed A-frag layout, see top
};

static __device__ __forceinline__ void store_feat(unsigned short* feats, int b, int k, float v) {
  int step = k >> 5, q = (k >> 3) & 3, j = k & 7;
  feats[((size_t)(b >> 4) * 18 + step) * 512 + (q * 16 + (b & 15)) * 8 + j] = f2bf(v);
}

template <int SLO, int SN>
static __device__ __forceinline__ void mfma_group(f32x4& acc, int s, const bfrag& Af,
                                                  const bfrag* BfBase) {
  if (s >= SLO && s < SLO + SN)
    acc = __builtin_amdgcn_mfma_f32_16x16x32_bf16(Af, BfBase[s - SLO], acc, 0, 0, 0);
}

// One 16-row MFMA tile over all 5 filter groups. arow = A base (already includes quad*8).
static __device__ __forceinline__ void tile_mfma(const unsigned short* arow, const bfrag* Bf,
                                                 f32x4 acc[5]) {
#pragma unroll
  for (int s = 0; s < 7; ++s) {
    bfrag Af = *(const bfrag*)(arow + s * 32);
    mfma_group<SLO0, SN0>(acc[0], s, Af, Bf + 0);
    mfma_group<SLO1, SN1>(acc[1], s, Af, Bf + 1);
    mfma_group<SLO2, SN2>(acc[2], s, Af, Bf + 4);
    mfma_group<SLO3, SN3>(acc[3], s, Af, Bf + 9);
    acc[4] = __builtin_amdgcn_mfma_f32_16x16x32_bf16(Af, Bf[15 + s], acc[4], 0, 0, 0);
  }
}

// SEQ6c==0: Lp = 1<<SHIFTc <= 16, one tile per job; invalid output rows (l>=Lc)
//           redirected to the zero scratch row (acc=0, inert under relu-max).
// SEQ6c==1: seq6 (L=18): 16 main tiles (rows 0-15) + 2 leftover tiles packing rows
//           {16,17} of 8 samples each; leftover partials merged via LDS.
template <int Lc, int SHIFTc, int SEQ6c, int TBBv, int Pv>
__device__ __forceinline__ void conv_body(unsigned short* xl, const ConvArgs& a,
                                          const int seq, const int b0) {
  const int tid = threadIdx.x;
  const float* xg = a.x[seq];

  // zero staging region incl. zero scratch (covers c-pad, l-pad, halo) — vectorized
  constexpr int ZWORDS = (SEQ6c ? TBBv * Pv * 24 : ZOFF + 256) / 8;
  for (int i = tid; i < ZWORDS; i += 256) ((uint4*)xl)[i] = uint4{0, 0, 0, 0};
  __syncthreads();
  // stage x -> bf16 [b][pos=xi+4][c]
  for (int r = tid; r < TBBv * 20; r += 256) {
    int b = r / 20, c = r % 20;
    const float* src = xg + ((size_t)(b0 + b) * 20 + c) * Lc;
    unsigned short* dst = xl + (b * Pv + 4) * 24 + c;
#pragma unroll
    for (int xi = 0; xi < Lc; ++xi) dst[xi * 24] = f2bf(src[xi]);
  }
  __syncthreads();

  const int wave = tid >> 6, lane = tid & 63, quad = lane >> 4, m = lane & 15;

  // preload the 22 non-zero B fragments for this seq
  const bfrag* wp = a.Wpack + (size_t)(seq * 5 * 7) * 64 + lane;
  bfrag Bf[22];
  {
    int bi = 0;
#pragma unroll
    for (int i = 0; i < SN0; ++i) Bf[bi++] = wp[(0 * 7 + SLO0 + i) * 64];
#pragma unroll
    for (int i = 0; i < SN1; ++i) Bf[bi++] = wp[(1 * 7 + SLO1 + i) * 64];
#pragma unroll
    for (int i = 0; i < SN2; ++i) Bf[bi++] = wp[(2 * 7 + SLO2 + i) * 64];
#pragma unroll
    for (int i = 0; i < SN3; ++i) Bf[bi++] = wp[(3 * 7 + SLO3 + i) * 64];
#pragma unroll
    for (int i = 0; i < SN4; ++i) Bf[bi++] = wp[(4 * 7 + SLO4 + i) * 64];
  }
  // Bf base offsets per nt: {0, 1, 4, 9, 15}

  float* part = (float*)(xl + PART_OFF);   // seq6 leftover partials [sample(16)][80]

  if (SEQ6c) {
    // leftover tiles: wave t in {0,1}: rows m -> sample t*8 + (m>>1), l = 16 + (m&1)
    if (wave < 2) {
      int bl = wave * 8 + (m >> 1), l = 16 + (m & 1);
      const unsigned short* arow = &xl[(bl * Pv + l) * 24 + quad * 8];
      f32x4 acc[5];
#pragma unroll
      for (int g = 0; g < 5; ++g) acc[g] = f32x4{0.f, 0.f, 0.f, 0.f};
      tile_mfma(arow, Bf, acc);
      // C row r=quad*4+r4 -> sample wave*8 + (r>>1): regs (0,1)->2q, (2,3)->2q+1
#pragma unroll
      for (int g = 0; g < 5; ++g) {
        float p0 = fmaxf(fmaxf(acc[g][0], acc[g][1]), 0.f);
        float p1 = fmaxf(fmaxf(acc[g][2], acc[g][3]), 0.f);
        part[(wave * 8 + 2 * quad) * 80 + g * 16 + m] = p0;
        part[(wave * 8 + 2 * quad + 1) * 80 + g * 16 + m] = p1;
      }
    }
    __syncthreads();
  }

  constexpr int njobs = SEQ6c ? TBBv : ((TBBv << SHIFTc) >> 4);
  constexpr int bpt = (!SEQ6c && SHIFTc == 3) ? 2 : 1;
  constexpr int lmask = (1 << SHIFTc) - 1;

  for (int job = wave; job < njobs; job += 4) {
    int bl, l;
    if (SEQ6c) { bl = job; l = m; }
    else { int r = job * 16 + m; bl = r >> SHIFTc; l = r & lmask; }
    // invalid output rows read the zero scratch instead of garbage windows
    const unsigned short* arow = (SEQ6c || l < Lc)
        ? &xl[(bl * Pv + l) * 24 + quad * 8]
        : &xl[ZOFF + quad * 8];
    f32x4 acc[5];
#pragma unroll
    for (int g = 0; g < 5; ++g) acc[g] = f32x4{0.f, 0.f, 0.f, 0.f};
    tile_mfma(arow, Bf, acc);

    float v0 = fmaxf(fmaxf(fmaxf(acc[0][0], acc[0][1]), fmaxf(acc[0][2], acc[0][3])), 0.f);
    float v1 = fmaxf(fmaxf(fmaxf(acc[1][0], acc[1][1]), fmaxf(acc[1][2], acc[1][3])), 0.f);
    float v2 = fmaxf(fmaxf(fmaxf(acc[2][0], acc[2][1]), fmaxf(acc[2][2], acc[2][3])), 0.f);
    float v3 = fmaxf(fmaxf(fmaxf(acc[3][0], acc[3][1]), fmaxf(acc[3][2], acc[3][3])), 0.f);
    float v4 = fmaxf(fmaxf(fmaxf(acc[4][0], acc[4][1]), fmaxf(acc[4][2], acc[4][3])), 0.f);
    v0 = fmaxf(v0, __shfl_xor(v0, 16));
    v1 = fmaxf(v1, __shfl_xor(v1, 16));
    v2 = fmaxf(v2, __shfl_xor(v2, 16));
    v3 = fmaxf(v3, __shfl_xor(v3, 16));
    v4 = fmaxf(v4, __shfl_xor(v4, 16));
    if (bpt == 1) {
      v0 = fmaxf(v0, __shfl_xor(v0, 32));
      v1 = fmaxf(v1, __shfl_xor(v1, 32));
      v2 = fmaxf(v2, __shfl_xor(v2, 32));
      v3 = fmaxf(v3, __shfl_xor(v3, 32));
      v4 = fmaxf(v4, __shfl_xor(v4, 32));
      if (lane < 16) {
        if (SEQ6c) {   // merge leftover-row partials
          v0 = fmaxf(v0, part[job * 80 + 0 + lane]);
          v1 = fmaxf(v1, part[job * 80 + 16 + lane]);
          v2 = fmaxf(v2, part[job * 80 + 32 + lane]);
          v3 = fmaxf(v3, part[job * 80 + 48 + lane]);
          v4 = fmaxf(v4, part[job * 80 + 64 + lane]);
        }
        int b = b0 + job, kb = seq * 80 + lane;
        store_feat(a.feats, b, kb, v0);      store_feat(a.feats, b, kb + 16, v1);
        store_feat(a.feats, b, kb + 32, v2); store_feat(a.feats, b, kb + 48, v3);
        store_feat(a.feats, b, kb + 64, v4);
      }
    } else {
      // out rows 0-7 (quads 0,1) -> even sample ; rows 8-15 (quads 2,3) -> odd
      if ((lane & 16) == 0) {
        int b = b0 + job * 2 + (lane >> 5), kb = seq * 80 + (lane & 15);
        store_feat(a.feats, b, kb, v0);      store_feat(a.feats, b, kb + 16, v1);
        store_feat(a.feats, b, kb + 32, v2); store_feat(a.feats, b, kb + 48, v3);
        store_feat(a.feats, b, kb + 64, v4);
      }
    }
  }
}

__global__ __launch_bounds__(256, 3) void conv_kernel(ConvArgs a) {
  __shared__ __align__(16) unsigned short xl[XL_HW];   // 43 KB -> 3 blocks/CU
  const int bid = blockIdx.x;
  if (bid < 3072) {
    const int seq = bid >> 9, b0 = (bid & 511) * 32;
    switch (seq) {
      case 0: conv_body<12, 4, 0, 32, 25>(xl, a, 0, b0); break;
      case 1: conv_body< 7, 3, 0, 32, 25>(xl, a, 1, b0); break;
      case 2: conv_body< 8, 3, 0, 32, 25>(xl, a, 2, b0); break;
      case 3: conv_body<16, 4, 0, 32, 25>(xl, a, 3, b0); break;
      case 4: conv_body< 6, 3, 0, 32, 25>(xl, a, 4, b0); break;
      default: conv_body< 7, 3, 0, 32, 25>(xl, a, 5, b0); break;
    }
  } else {
    conv_body<18, 5, 1, 16, 41>(xl, a, 6, (bid - 3072) * 16);
  }
}

// ---------------- MLP: feats(packed) -> sigmoid(@lin1^T+b1) -> @lin2^T+b2 ----------------
struct MlpArgs {
  const bfrag* feats;      // packed A-frag layout
  const bfrag* lin1pack;
  const float* lin1_b;
  const float* lin2_w;
  const float* lin2_b;
  float* out;
};

__global__ __launch_bounds__(256, 4) void mlp_kernel(MlpArgs a) {
  __shared__ float h[16 * 68];
  __shared__ float w2[64];
  const int tid = threadIdx.x;
  const int b0 = blockIdx.x * 16;
  if (tid < 64) w2[tid] = a.lin2_w[tid];
  const int wave = tid >> 6, lane = tid & 63, quad = lane >> 4, m = lane & 15;
  const int nt = wave;                     // one n-tile per wave
  bfrag Bf[18];
#pragma unroll
  for (int s = 0; s < 18; ++s) Bf[s] = a.lin1pack[(nt * 18 + s) * 64 + lane];
  const bfrag* ap = a.feats + (size_t)blockIdx.x * 18 * 64 + lane;  // coalesced 16B/lane
  f32x4 acc = {0.f, 0.f, 0.f, 0.f};
#pragma unroll
  for (int s = 0; s < 18; ++s)
    acc = __builtin_amdgcn_mfma_f32_16x16x32_bf16(ap[s * 64], Bf[s], acc, 0, 0, 0);
  int n = nt * 16 + m;
  float bias = a.lin1_b[n];
#pragma unroll
  for (int r = 0; r < 4; ++r) {
    float pre = acc[r] + bias;
    h[(quad * 4 + r) * 68 + n] = 1.f / (1.f + __expf(-pre));
  }
  __syncthreads();
  int bl = tid >> 4, q = tid & 15;         // 16 threads per sample, 4 h each
  const float* hr = &h[bl * 68 + q * 4];
  float s = hr[0] * w2[q * 4] + hr[1] * w2[q * 4 + 1] + hr[2] * w2[q * 4 + 2] + hr[3] * w2[q * 4 + 3];
  s += __shfl_xor(s, 1);
  s += __shfl_xor(s, 2);
  s += __shfl_xor(s, 4);
  s += __shfl_xor(s, 8);
  if (q == 0) a.out[b0 + bl] = s + a.lin2_b[0];
}

// ---------------- launch ----------------
extern "C" void kernel_launch(void* const* d_in, const int* in_sizes, int n_in,
                              void* d_out, int out_size, void* d_ws, size_t ws_size,
                              hipStream_t stream) {
  (void)in_sizes; (void)n_in; (void)out_size; (void)ws_size;
  char* ws = (char*)d_ws;
  bfrag* Wpack = (bfrag*)(ws + 0);                 // 15680*16 = 250,880 B
  bfrag* lin1pack = (bfrag*)(ws + 262144);         // 4608*16  =  73,728 B
  unsigned short* feats = (unsigned short*)(ws + 393216);  // 1024*18*64*16 = 18.87 MB

  PrepArgs pa;
  for (int j = 0; j < 5; ++j) pa.Wk[j] = (const float*)d_in[7 + j];
  pa.lin1_w = (const float*)d_in[12];
  pa.Wpack = Wpack;
  pa.lin1pack = lin1pack;
  prep_kernel<<<80, 256, 0, stream>>>(pa);

  ConvArgs ca;
  for (int i = 0; i < NSEQ; ++i) ca.x[i] = (const float*)d_in[i];
  ca.Wpack = Wpack;
  ca.feats = feats;
  // 3072 blocks: seqs 0-5 (TBB=32) ; 1024 blocks: seq 6 (TBB=16)
  conv_kernel<<<4096, 256, 0, stream>>>(ca);

  MlpArgs ma;
  ma.feats = (const bfrag*)feats;
  ma.lin1pack = lin1pack;
  ma.lin1_b = (const float*)d_in[13];
  ma.lin2_w = (const float*)d_in[14];
  ma.lin2_b = (const float*)d_in[15];
  ma.out = (float*)d_out;
  mlp_kernel<<<1024, 256, 0, stream>>>(ma);
}